// Round 7
// baseline (94.431 us; speedup 1.0000x reference)
//
#include <hip/hip_runtime.h>
#include <math.h>

#define KK 40
#define HH 16
#define DD 128
#define NN 512
#define X0C 0.085f
#define LOG2E 1.4426950408889634f
#define LN2f 0.6931471805599453f
#define SCB 17.0f   // per-step 2^-17 scaling folded into P~
#define NB 256      // mega-kernel grid (1 block/CU guaranteed co-resident)

// ws layout (float offsets). ~4.8 MB of the ~768 MB workspace.
enum {
  OFF_AW   = 0,                  // 512*16  fwd RNN drive
  OFF_BW   = OFF_AW + NN*HH,     // 512*16  bwd RNN drive
  OFF_WPB  = OFF_BW + NN*HH,     // 512*40  UwB @ W
  OFF_WBG  = OFF_WPB + NN*KK,    // 512*40  rowsum WlinB[words]
  OFF_TB   = OFF_WBG + NN*KK,    // 40*40
  OFF_H    = OFF_TB + KK*KK,     // 514*16
  OFF_HP   = OFF_H + 514*HH,     // 514*16
  OFF_A0   = OFF_HP + 514*HH,    // 40*40 x4 Taylor tables
  OFF_A1   = OFF_A0 + KK*KK,
  OFF_A2   = OFF_A1 + KK*KK,
  OFF_A3   = OFF_A2 + KK*KK,
  OFF_LA0  = OFF_A3 + KK*KK,     // 40
  OFF_FIN  = OFF_LA0 + KK,       // 40
  OFF_LACC = OFF_FIN + KK,       // 128 per-chunk log norms
  OFF_VL   = OFF_LACC + 128,     // 40 final direction
  OFF_CTR  = OFF_VL + 40,        // 8 (finisher counter, int slot 0)
  OFF_BAR  = OFF_CTR + 8,        // 8 (grid barrier: ctr[4], flag[4])
  OFF_D    = OFF_BAR + 8,        // 64000*4 sigma-derivative tables (16B aligned)
  OFF_PT   = OFF_D + KK*KK*KK*4, // 511*1600 P~ matrices
  WS_FLOATS = OFF_PT + 511*KK*KK
};

__device__ __forceinline__ float sigm(float x) {
  return 1.f / (1.f + __expf(-x));
}

// Device-scope grid barrier. State zeroed by ka_prep each launch (replay-safe).
// Release: threadfence before ctr-add; flag set only after all NB adds.
// Acquire: atomic poll of flag (coherence point, cross-XCD safe) + threadfence.
__device__ __forceinline__ void gbar(float* ws, int k) {
  unsigned* ctr  = (unsigned*)(ws + OFF_BAR) + k;
  unsigned* flag = (unsigned*)(ws + OFF_BAR) + 4 + k;
  __syncthreads();
  if (threadIdx.x == 0) {
    __threadfence();
    unsigned old = atomicAdd(ctr, 1u);
    if (old == (unsigned)(NB - 1)) {
      atomicExch(flag, 1u);
    } else {
      while (atomicAdd(flag, 0u) == 0u) __builtin_amdgcn_s_sleep(8);
    }
    __threadfence();
  }
  __syncthreads();
}

// KA: fused prep. Blocks 0..511: per-word gathers; block 512: TB = UtB@T^T +
//     zero finisher/barrier state; blocks 513..552: sigma-derivative tables.
__global__ __launch_bounds__(256) void ka_prep(
    const float* __restrict__ E, const float* __restrict__ M, const float* __restrict__ MP,
    const float* __restrict__ T, const float* __restrict__ UA, const float* __restrict__ UB,
    const float* __restrict__ WlinB, const int* __restrict__ words, float* __restrict__ ws)
{
  int b = blockIdx.x, t = threadIdx.x;
  if (b < NN) {
    __shared__ float wrow[DD];
    __shared__ float brow[KK*KK];
    int w = words[b];
    if (t < DD) wrow[t] = E[w*DD + t];
    for (int idx = t; idx < KK*KK; idx += 256) brow[idx] = WlinB[(size_t)w*(KK*KK) + idx];
    __syncthreads();
    if (t < 16) {                       // aw: M[:,17:145] @ w
      float acc = 0.f; const float* mr = M + t*145 + 17;
      for (int d = 0; d < DD; ++d) acc += mr[d]*wrow[d];
      ws[OFF_AW + b*HH + t] = acc;
    } else if (t < 32) {                // bw: MP[:,1:129] @ w
      int j = t - 16; float acc = 0.f; const float* mr = MP + j*145 + 1;
      for (int d = 0; d < DD; ++d) acc += mr[d]*wrow[d];
      ws[OFF_BW + b*HH + j] = acc;
    } else if (t < 72) {                // wpartB: UB[:,145:273] @ w
      int o = t - 32; float acc = 0.f; const float* ur = UB + o*289 + 145;
      for (int d = 0; d < DD; ++d) acc += ur[d]*wrow[d];
      ws[OFF_WPB + b*KK + o] = acc;
    }
    if (t < KK) {                       // WBg[b,u] = sum_s WlinB[w, s*40+u]
      float acc = 0.f;
      for (int s = 0; s < KK; ++s) acc += brow[s*KK + t];
      ws[OFF_WBG + b*KK + t] = acc;
    }
  } else if (b == NN) {                 // TB = UtB @ T^T + state reset
    if (t < 16) ((unsigned*)(ws + OFF_CTR))[t] = 0u;   // CTR[8] + BAR[8]
    __shared__ float Tl[KK*DD];
    for (int idx = t; idx < KK*DD; idx += 256) Tl[idx] = T[idx];
    __syncthreads();
    for (int out = t; out < KK*KK; out += 256) {
      int r = out / KK, s = out % KK;
      const float* ur = UB + r*289 + 145;
      float acc = 0.f;
      for (int d = 0; d < DD; ++d) acc += ur[d]*Tl[s*DD + d];
      ws[OFF_TB + out] = acc;
    }
  } else {                              // sigma-derivative tables, r = b-513
    int r = b - (NN + 1);
    __shared__ float ur[2*DD];
    __shared__ float sa[KK], ta[KK];
    if (t < DD) ur[t] = UA[r*289 + 17 + t];                 // UsA row
    else if (t < 2*DD) ur[t] = UA[r*289 + 145 + (t - DD)];  // UtA row
    __syncthreads();
    if (t < KK) {
      float acc = 0.f; const float* tr = T + t*DD;
      for (int d = 0; d < DD; ++d) acc += ur[d]*tr[d];
      sa[t] = acc;
    } else if (t >= 64 && t < 64 + KK) {
      int s = t - 64; float acc = 0.f; const float* tr = T + s*DD;
      for (int d = 0; d < DD; ++d) acc += ur[DD + d]*tr[d];
      ta[s] = acc;
    }
    __syncthreads();
    float4* dp = (float4*)(ws + OFF_D) + (size_t)r*1600;
    for (int st = t; st < KK*KK; st += 256) {
      int s = st / KK, u = st - s*KK;
      float y = X0C + sa[s] + ta[u];
      float sg = sigm(y);
      float s1 = sg*(1.f - sg);
      float d2 = s1*(1.f - 2.f*sg)*0.5f;
      float d3 = s1*(1.f - 6.f*sg*(1.f - sg))*(1.f/6.f);
      dp[st] = make_float4(sg, s1, d2, d3);
    }
  }
}

// KM: mega-kernel. Phase A: RNN (waves 0..31) + Taylor-MAC (waves 32..191).
//     gbar(0). Phase B: per-position expansion (block-strided tasks, A/TB in LDS).
//     gbar(1). Phase C: register chunk-scan (waves 0..127) + atomic finisher.
__global__ __launch_bounds__(256) void km_mega(
    const float* __restrict__ M, const float* __restrict__ MP,
    const float* __restrict__ WlinA, const float* __restrict__ UA,
    const float* __restrict__ UB, float* __restrict__ ws, float* __restrict__ out)
{
  int tid = threadIdx.x;
  int lane = tid & 63;
  int wv = (blockIdx.x << 2) + (tid >> 6);   // global wave id 0..1023

  // ---------------- Phase A ----------------
  if (wv < 32) {
    // RNN: |dh'/dh| <= 0.04/step => 8 warm-up steps from 0: err ~7e-12.
    int row = lane & 15;
    int g = wv*4 + (lane >> 4);         // 0..127
    int dirb = g >> 6;                  // 0 fwd, 1 bwd
    int c = g & 63;
    const float* Mat = dirb ? MP : M;
    const float* drv = ws + (dirb ? OFF_BW : OFF_AW);
    float* outh = ws + (dirb ? OFF_HP : OFF_H);
    float base = Mat[row*145];
    int hoff = dirb ? 129 : 1;
    float mh[HH];
    #pragma unroll
    for (int k = 0; k < HH; ++k) mh[k] = Mat[row*145 + hoff + k];
    float dr[16];
    #pragma unroll
    for (int j = 0; j < 16; ++j) {
      int i = dirb ? (8*c + 15 - j) : (8*c - 8 + j);
      int ic = min(max(i, 0), NN - 1);
      dr[j] = drv[ic*HH + row];
    }
    float h = 0.f;
    #pragma unroll
    for (int j = 0; j < 16; ++j) {
      int i = dirb ? (8*c + 15 - j) : (8*c - 8 + j);
      bool valid = (i >= 0) && (i < NN);
      float acc = base + dr[j];
      #pragma unroll
      for (int k = 0; k < HH; ++k) acc += mh[k] * __shfl(h, k, 16);
      float h2 = sigm(acc);
      if (valid) h = h2;
      if (valid && j >= 8) outh[(i + 1)*HH + row] = h;
    }
    if (wv == 0 && lane < 16) {
      ws[OFF_H + lane] = 0.f;  ws[OFF_H + 513*HH + lane] = 0.f;
      ws[OFF_HP + lane] = 0.f; ws[OFF_HP + 513*HH + lane] = 0.f;
    }
  } else if (wv < 192) {
    // MAC: A_m[r,o] = sum_st D_m[r,st]*WlinA[o,st]; (o, r-quarter) per wave.
    int bb = wv - 32;
    int o = bb >> 2, q = bb & 3;
    int j = lane;
    float wreg[25];
    #pragma unroll
    for (int k = 0; k < 25; ++k) wreg[k] = WlinA[o*1600 + j + 64*k];
    for (int rr = 0; rr < 10; ++rr) {
      int r = q*10 + rr;
      const float4* dp = (const float4*)(ws + OFF_D) + (size_t)r*1600;
      float a0 = 0, a1 = 0, a2 = 0, a3 = 0;
      #pragma unroll
      for (int k = 0; k < 25; ++k) {
        float4 d = dp[j + 64*k];
        float wl = wreg[k];
        a0 += d.x*wl; a1 += d.y*wl; a2 += d.z*wl; a3 += d.w*wl;
      }
      #pragma unroll
      for (int m = 1; m <= 32; m <<= 1) {
        a0 += __shfl_xor(a0, m); a1 += __shfl_xor(a1, m);
        a2 += __shfl_xor(a2, m); a3 += __shfl_xor(a3, m);
      }
      if (j == 0) {
        ws[OFF_A0 + r*KK + o] = a0; ws[OFF_A1 + r*KK + o] = a1;
        ws[OFF_A2 + r*KK + o] = a2; ws[OFF_A3 + r*KK + o] = a3;
      }
    }
  }

  gbar(ws, 0);

  // ---------------- Phase B ----------------
  __shared__ __align__(16) float sA0[KK*KK], sA1[KK*KK], sA2[KK*KK], sA3[KK*KK];
  __shared__ float tbl[KK][KK + 1];
  __shared__ float hl[16], hal[16], hbl[16];
  __shared__ float wbg[KK], prA[KK], aB[KK], el[KK];
  __shared__ float ep[4][KK];
  for (int idx = tid; idx < KK*KK; idx += 256) {
    sA0[idx] = ws[OFF_A0 + idx]; sA1[idx] = ws[OFF_A1 + idx];
    sA2[idx] = ws[OFF_A2 + idx]; sA3[idx] = ws[OFF_A3 + idx];
    tbl[idx / KK][idx % KK] = ws[OFF_TB + idx];
  }
  for (int i = blockIdx.x; i < NN + 1; i += NB) {
    __syncthreads();                    // staging done / smem reuse
    bool hasE = (i < NN);
    if (tid < 16) {
      hl[tid]  = ws[OFF_H + i*HH + tid];
      hal[tid] = (i >= 2) ? ws[OFF_HP + (i - 2)*HH + tid] : 0.f;
      hbl[tid] = (i >= 1) ? ws[OFF_HP + (i - 1)*HH + tid] : 0.f;
    }
    if (hasE && tid < KK) wbg[tid] = ws[OFF_WBG + i*KK + tid];
    __syncthreads();
    if (tid < KK) {
      const float* ua = UA + tid*289;
      float accA = ua[0];
      #pragma unroll
      for (int k2 = 0; k2 < HH; ++k2) accA += hl[k2]*ua[1 + k2] + hal[k2]*ua[273 + k2];
      prA[tid] = accA;
      if (hasE) {
        const float* ub = UB + tid*289;
        float accB = ub[0] + ((i >= 1) ? ws[OFF_WPB + (i - 1)*KK + tid] : 0.f);
        #pragma unroll
        for (int k2 = 0; k2 < HH; ++k2) accB += hl[k2]*ub[1 + k2] + hbl[k2]*ub[273 + k2];
        aB[tid] = accB;
      }
    }
    __syncthreads();
    if (hasE && tid < 4*KK) {
      int t = tid % KK, g = tid / KK;
      float accB = aB[t];
      float p = 0.f;
      #pragma unroll
      for (int j = 0; j < 10; ++j) {
        int u = g*10 + j;
        p += wbg[u] * sigm(accB + tbl[t][u]);
      }
      ep[g][t] = p;
    }
    __syncthreads();
    if (tid < KK) el[tid] = hasE ? (ep[0][tid] + ep[1][tid] + ep[2][tid] + ep[3][tid]) : 0.f;
    __syncthreads();
    const float4* A0 = (const float4*)sA0;
    const float4* A1 = (const float4*)sA1;
    const float4* A2 = (const float4*)sA2;
    const float4* A3 = (const float4*)sA3;
    float4* pt4 = (float4*)(ws + OFF_PT + (size_t)(i - 1)*1600);
    for (int f = tid; f < 400; f += 256) {
      int idx = f*4;
      float4 c0 = A0[f], c1 = A1[f], c2 = A2[f], c3 = A3[f];
      const float* p0 = (const float*)&c0; const float* p1 = (const float*)&c1;
      const float* p2 = (const float*)&c2; const float* p3 = (const float*)&c3;
      float res[4];
      #pragma unroll
      for (int j = 0; j < 4; ++j) {
        int id = idx + j;
        int r = id / KK, o = id - r*KK;
        float d = prA[r] - X0C;
        float lp = ((p3[j]*d + p2[j])*d + p1[j])*d + p0[j];
        if (i == 0) {
          if (r == 0) ws[OFF_LA0 + o] = lp + el[o];
          res[j] = 0.f;
        } else if (i == NN) {
          if (o == 1) ws[OFF_FIN + r] = lp;
          res[j] = 0.f;
        } else {
          res[j] = exp2f((lp + el[o])*LOG2E - SCB);
        }
      }
      if (i > 0 && i < NN) pt4[f] = make_float4(res[0], res[1], res[2], res[3]);
    }
  }

  gbar(ws, 1);

  // ---------------- Phase C ----------------
  if (wv < 128) {
    int c = wv;
    int o = min(lane, KK - 1);
    int s0 = 4*c;
    int len = min(4, 511 - s0);
    int w0 = (s0 >= 4) ? (s0 - 4) : 0;
    int nst = s0 + len - w0;
    const float* P = ws + OFF_PT;
    float lacc = 0.f;
    float v;
    if (w0 == 0) {
      float la = ws[OFF_LA0 + o];
      float m0 = la;
      #pragma unroll
      for (int m = 1; m <= 32; m <<= 1) m0 = fmaxf(m0, __shfl_xor(m0, m));
      v = __expf(la - m0);
      if (c == 0) lacc = m0;
    } else {
      v = 1.f;
    }
    float pcA[KK], pcB[KK];

#define LOADCOL(buf, pi) do {                                   \
    const float* g_ = P + (size_t)(pi)*1600 + o;                \
    _Pragma("unroll")                                           \
    for (int r_ = 0; r_ < KK; ++r_) buf[r_] = g_[r_*KK];        \
  } while (0)

#define MSTEP(cur, nxt, k) do {                                 \
    if ((k) + 1 < nst) LOADCOL(nxt, w0 + (k) + 1);              \
    float a0_ = 0, a1_ = 0, a2_ = 0, a3_ = 0;                   \
    _Pragma("unroll")                                           \
    for (int r_ = 0; r_ < KK; r_ += 4) {                        \
      a0_ += __shfl(v, r_ + 0, 64)*cur[r_ + 0];                 \
      a1_ += __shfl(v, r_ + 1, 64)*cur[r_ + 1];                 \
      a2_ += __shfl(v, r_ + 2, 64)*cur[r_ + 2];                 \
      a3_ += __shfl(v, r_ + 3, 64)*cur[r_ + 3];                 \
    }                                                           \
    float s_ = (a0_ + a1_) + (a2_ + a3_);                       \
    if ((((k) + 1) & 3) == 0 || (k) == nst - 1) {               \
      float mx_ = s_;                                           \
      _Pragma("unroll")                                         \
      for (int m_ = 1; m_ <= 32; m_ <<= 1)                      \
        mx_ = fmaxf(mx_, __shfl_xor(mx_, m_));                  \
      v = s_ / mx_;                                             \
      if (w0 + ((k) & ~3) >= s0)                                \
        lacc += __logf(mx_) + (float)(((k) & 3) + 1)*(SCB*LN2f);\
    } else {                                                    \
      v = s_;                                                   \
    }                                                           \
  } while (0)

    LOADCOL(pcA, w0);
    int k = 0;
    while (k + 2 <= nst) {
      MSTEP(pcA, pcB, k);
      MSTEP(pcB, pcA, k + 1);
      k += 2;
    }
    if (k < nst) MSTEP(pcA, pcB, k);
#undef MSTEP
#undef LOADCOL

    if (lane == 0) ws[OFF_LACC + c] = lacc;
    if (c == 127 && lane < KK) ws[OFF_VL + lane] = v;
    __threadfence();
    int last = 0;
    if (lane == 0) {
      int old = atomicAdd((int*)(ws + OFF_CTR), 1);
      last = (old == 127);
    }
    last = __shfl(last, 0, 64);
    if (last) {
      __threadfence();
      float l = ws[OFF_LACC + lane] + ws[OFF_LACC + 64 + lane];
      #pragma unroll
      for (int m = 1; m <= 32; m <<= 1) l += __shfl_xor(l, m);
      float tv = (lane < KK) ? ws[OFF_VL + lane]*__expf(ws[OFF_FIN + lane]) : 0.f;
      #pragma unroll
      for (int m = 1; m <= 32; m <<= 1) tv += __shfl_xor(tv, m);
      if (lane == 0) out[0] = l + __logf(tv);
    }
  }
}

extern "C" void kernel_launch(void* const* d_in, const int* in_sizes, int n_in,
                              void* d_out, int out_size, void* d_ws, size_t ws_size,
                              hipStream_t stream) {
  const float* E     = (const float*)d_in[0];
  const float* M     = (const float*)d_in[1];
  const float* MP    = (const float*)d_in[2];
  const float* T     = (const float*)d_in[3];
  const float* UA    = (const float*)d_in[4];
  const float* UB    = (const float*)d_in[5];
  const float* WlinA = (const float*)d_in[6];
  const float* WlinB = (const float*)d_in[7];
  const int*   words = (const int*)d_in[8];
  float* ws  = (float*)d_ws;
  float* out = (float*)d_out;

  ka_prep<<<dim3(NN + 1 + KK), dim3(256), 0, stream>>>(E, M, MP, T, UA, UB, WlinB, words, ws);
  km_mega<<<dim3(NB), dim3(256), 0, stream>>>(M, MP, WlinA, UA, UB, ws, out);
}

// Round 8
// 60.400 us; speedup vs baseline: 1.5634x; 1.5634x over previous
//
#include <hip/hip_runtime.h>
#include <math.h>

#define KK 40
#define HH 16
#define DD 128
#define NN 512
#define X0C 0.085f
#define LOG2E 1.4426950408889634f
#define LN2f 0.6931471805599453f
#define SCB 17.0f   // per-step 2^-17 scaling folded into P~

// ws layout (float offsets). ~4.8 MB of the ~768 MB workspace.
// A-tables and PT are stored TRANSPOSED (o-major) for coalesced scan loads.
enum {
  OFF_AW   = 0,                  // 512*16  fwd RNN drive
  OFF_BW   = OFF_AW + NN*HH,     // 512*16  bwd RNN drive
  OFF_WPB  = OFF_BW + NN*HH,     // 512*40  UwB @ W
  OFF_WBG  = OFF_WPB + NN*KK,    // 512*40  rowsum WlinB[words]
  OFF_TB   = OFF_WBG + NN*KK,    // 40*40
  OFF_H    = OFF_TB + KK*KK,     // 514*16
  OFF_HP   = OFF_H + 514*HH,     // 514*16
  OFF_A0   = OFF_HP + 514*HH,    // 40*40 x4 Taylor tables, layout [o][r]
  OFF_A1   = OFF_A0 + KK*KK,
  OFF_A2   = OFF_A1 + KK*KK,
  OFF_A3   = OFF_A2 + KK*KK,
  OFF_LA0  = OFF_A3 + KK*KK,     // 40
  OFF_FIN  = OFF_LA0 + KK,       // 40
  OFF_LACC = OFF_FIN + KK,       // 128 per-chunk log norms
  OFF_VL   = OFF_LACC + 128,     // 40 final direction
  OFF_CTR  = OFF_VL + 40,        // 8 (finisher counter, int slot 0)
  OFF_D    = OFF_CTR + 8,        // 64000*4 sigma-derivative tables (16B aligned)
  OFF_PT   = OFF_D + KK*KK*KK*4, // 511*1600 P~^T matrices, layout [i][o][r]
  WS_FLOATS = OFF_PT + 511*KK*KK
};

__device__ __forceinline__ float sigm(float x) {
  return 1.f / (1.f + __expf(-x));
}

// KA: fused prep. Blocks 0..511: per-word gathers; block 512: TB = UtB@T^T +
//     zero finisher counter; blocks 513..552: sigma-derivative tables.
__global__ __launch_bounds__(256) void ka_prep(
    const float* __restrict__ E, const float* __restrict__ M, const float* __restrict__ MP,
    const float* __restrict__ T, const float* __restrict__ UA, const float* __restrict__ UB,
    const float* __restrict__ WlinB, const int* __restrict__ words, float* __restrict__ ws)
{
  int b = blockIdx.x, t = threadIdx.x;
  if (b < NN) {
    __shared__ float wrow[DD];
    int w = words[b];
    if (t < DD) wrow[t] = E[w*DD + t];
    if (t < KK) {                       // WBg[b,u] = sum_s WlinB[w, s*40+u], coalesced
      const float* wb = WlinB + (size_t)w*(KK*KK) + t;
      float acc = 0.f;
      #pragma unroll 8
      for (int s = 0; s < KK; ++s) acc += wb[s*KK];
      ws[OFF_WBG + b*KK + t] = acc;
    }
    __syncthreads();
    if (t < 16) {                       // aw: M[:,17:145] @ w
      float acc = 0.f; const float* mr = M + t*145 + 17;
      for (int d = 0; d < DD; ++d) acc += mr[d]*wrow[d];
      ws[OFF_AW + b*HH + t] = acc;
    } else if (t < 32) {                // bw: MP[:,1:129] @ w
      int j = t - 16; float acc = 0.f; const float* mr = MP + j*145 + 1;
      for (int d = 0; d < DD; ++d) acc += mr[d]*wrow[d];
      ws[OFF_BW + b*HH + j] = acc;
    } else if (t < 72) {                // wpartB: UB[:,145:273] @ w
      int o = t - 32; float acc = 0.f; const float* ur = UB + o*289 + 145;
      for (int d = 0; d < DD; ++d) acc += ur[d]*wrow[d];
      ws[OFF_WPB + b*KK + o] = acc;
    }
  } else if (b == NN) {                 // TB = UtB @ T^T + counter reset
    if (t < 8) ((unsigned*)(ws + OFF_CTR))[t] = 0u;
    __shared__ float Tl[KK*DD];
    for (int idx = t; idx < KK*DD; idx += 256) Tl[idx] = T[idx];
    __syncthreads();
    for (int out = t; out < KK*KK; out += 256) {
      int r = out / KK, s = out % KK;
      const float* ur = UB + r*289 + 145;
      float acc = 0.f;
      for (int d = 0; d < DD; ++d) acc += ur[d]*Tl[s*DD + d];
      ws[OFF_TB + out] = acc;
    }
  } else {                              // sigma-derivative tables, r = b-513
    int r = b - (NN + 1);
    __shared__ float ur[2*DD];
    __shared__ float sa[KK], ta[KK];
    if (t < DD) ur[t] = UA[r*289 + 17 + t];                 // UsA row
    else if (t < 2*DD) ur[t] = UA[r*289 + 145 + (t - DD)];  // UtA row
    __syncthreads();
    if (t < KK) {
      float acc = 0.f; const float* tr = T + t*DD;
      for (int d = 0; d < DD; ++d) acc += ur[d]*tr[d];
      sa[t] = acc;
    } else if (t >= 64 && t < 64 + KK) {
      int s = t - 64; float acc = 0.f; const float* tr = T + s*DD;
      for (int d = 0; d < DD; ++d) acc += ur[DD + d]*tr[d];
      ta[s] = acc;
    }
    __syncthreads();
    float4* dp = (float4*)(ws + OFF_D) + (size_t)r*1600;
    for (int st = t; st < KK*KK; st += 256) {
      int s = st / KK, u = st - s*KK;
      float y = X0C + sa[s] + ta[u];
      float sg = sigm(y);
      float s1 = sg*(1.f - sg);
      float d2 = s1*(1.f - 2.f*sg)*0.5f;
      float d3 = s1*(1.f - 6.f*sg*(1.f - sg))*(1.f/6.f);
      dp[st] = make_float4(sg, s1, d2, d3);
    }
  }
}

// KB: fused RNN + Taylor-MAC (both depend only on KA). Blocks 0..31: chunk-parallel
// RNN scans. Blocks 32..191: A_m[o][r] reductions (note TRANSPOSED write).
__global__ __launch_bounds__(64) void kb_rnn_mac(const float* __restrict__ M,
                                                 const float* __restrict__ MP,
                                                 const float* __restrict__ WlinA,
                                                 float* __restrict__ ws)
{
  int b = blockIdx.x;
  int lane = threadIdx.x;
  if (b < 32) {
    // RNN: |dh'/dh| <= 0.04/step => 8 warm-up steps from 0: err ~7e-12.
    int row = lane & 15;
    int g = b*4 + (lane >> 4);          // 0..127
    int dirb = g >> 6;                  // 0 fwd, 1 bwd
    int c = g & 63;
    const float* Mat = dirb ? MP : M;
    const float* drv = ws + (dirb ? OFF_BW : OFF_AW);
    float* out = ws + (dirb ? OFF_HP : OFF_H);
    float base = Mat[row*145];
    int hoff = dirb ? 129 : 1;
    float mh[HH];
    #pragma unroll
    for (int k = 0; k < HH; ++k) mh[k] = Mat[row*145 + hoff + k];
    float dr[16];
    #pragma unroll
    for (int j = 0; j < 16; ++j) {
      int i = dirb ? (8*c + 15 - j) : (8*c - 8 + j);
      int ic = min(max(i, 0), NN - 1);
      dr[j] = drv[ic*HH + row];
    }
    float h = 0.f;
    #pragma unroll
    for (int j = 0; j < 16; ++j) {
      int i = dirb ? (8*c + 15 - j) : (8*c - 8 + j);
      bool valid = (i >= 0) && (i < NN);
      float acc = base + dr[j];
      #pragma unroll
      for (int k = 0; k < HH; ++k) acc += mh[k] * __shfl(h, k, 16);
      float h2 = sigm(acc);
      if (valid) h = h2;
      if (valid && j >= 8) out[(i + 1)*HH + row] = h;
    }
    if (b == 0 && lane < 16) {
      ws[OFF_H + lane] = 0.f;  ws[OFF_H + 513*HH + lane] = 0.f;
      ws[OFF_HP + lane] = 0.f; ws[OFF_HP + 513*HH + lane] = 0.f;
    }
  } else {
    // MAC: A_m[o][r] = sum_st D_m[r,st]*WlinA[o,st]; (o, r-quarter) per block.
    int bb = b - 32;
    int o = bb >> 2, q = bb & 3;
    int j = lane;
    float wreg[25];
    #pragma unroll
    for (int k = 0; k < 25; ++k) wreg[k] = WlinA[o*1600 + j + 64*k];
    for (int rr = 0; rr < 10; ++rr) {
      int r = q*10 + rr;
      const float4* dp = (const float4*)(ws + OFF_D) + (size_t)r*1600;
      float a0 = 0, a1 = 0, a2 = 0, a3 = 0;
      #pragma unroll
      for (int k = 0; k < 25; ++k) {
        float4 d = dp[j + 64*k];
        float wl = wreg[k];
        a0 += d.x*wl; a1 += d.y*wl; a2 += d.z*wl; a3 += d.w*wl;
      }
      #pragma unroll
      for (int m = 1; m <= 32; m <<= 1) {
        a0 += __shfl_xor(a0, m); a1 += __shfl_xor(a1, m);
        a2 += __shfl_xor(a2, m); a3 += __shfl_xor(a3, m);
      }
      if (j == 0) {                      // transposed write [o][r]
        ws[OFF_A0 + o*KK + r] = a0; ws[OFF_A1 + o*KK + r] = a1;
        ws[OFF_A2 + o*KK + r] = a2; ws[OFF_A3 + o*KK + r] = a3;
      }
    }
  }
}

// KD: fused per-position kernel. Block i (0..512):
//  - preA[r] and accB[t] from h/hp (exact); e[t] via 160-thread split
//  - cubic-Horner expansion; emit P~^T[i-1] ([o][r], coalesced), or LA0/FIN.
__global__ __launch_bounds__(256) void kd_expand(const float* __restrict__ UA,
                                                 const float* __restrict__ UB,
                                                 float* __restrict__ ws)
{
  int i = blockIdx.x;   // 0..512
  int tid = threadIdx.x;
  __shared__ float hl[16], hal[16], hbl[16];
  __shared__ float tbl[KK][KK + 1];
  __shared__ float wbg[KK];
  __shared__ float prA[KK], aB[KK], el[KK];
  __shared__ float ep[4][KK];
  bool hasE = (i < NN);
  if (tid < 16) {
    hl[tid]  = ws[OFF_H + i*HH + tid];
    hal[tid] = (i >= 2) ? ws[OFF_HP + (i - 2)*HH + tid] : 0.f;
    hbl[tid] = (i >= 1) ? ws[OFF_HP + (i - 1)*HH + tid] : 0.f;
  }
  if (hasE) {
    for (int idx = tid; idx < KK*KK; idx += 256) tbl[idx / KK][idx % KK] = ws[OFF_TB + idx];
    if (tid < KK) wbg[tid] = ws[OFF_WBG + i*KK + tid];
  }
  __syncthreads();
  if (tid < KK) {
    const float* ua = UA + tid*289;
    float accA = ua[0];
    #pragma unroll
    for (int k2 = 0; k2 < HH; ++k2) accA += hl[k2]*ua[1 + k2] + hal[k2]*ua[273 + k2];
    prA[tid] = accA;
    if (hasE) {
      const float* ub = UB + tid*289;
      float accB = ub[0] + ((i >= 1) ? ws[OFF_WPB + (i - 1)*KK + tid] : 0.f);
      #pragma unroll
      for (int k2 = 0; k2 < HH; ++k2) accB += hl[k2]*ub[1 + k2] + hbl[k2]*ub[273 + k2];
      aB[tid] = accB;
    }
  }
  __syncthreads();
  if (hasE && tid < 4*KK) {
    int t = tid % KK, g = tid / KK;
    float accB = aB[t];
    float p = 0.f;
    #pragma unroll
    for (int j = 0; j < 10; ++j) {
      int u = g*10 + j;
      p += wbg[u] * sigm(accB + tbl[t][u]);
    }
    ep[g][t] = p;
  }
  __syncthreads();
  if (tid < KK) el[tid] = hasE ? (ep[0][tid] + ep[1][tid] + ep[2][tid] + ep[3][tid]) : 0.f;
  __syncthreads();
  const float4* A0 = (const float4*)(ws + OFF_A0);   // [o][r] layout
  const float4* A1 = (const float4*)(ws + OFF_A1);
  const float4* A2 = (const float4*)(ws + OFF_A2);
  const float4* A3 = (const float4*)(ws + OFF_A3);
  float4* pt4 = (float4*)(ws + OFF_PT + (size_t)(i - 1)*1600);
  for (int f = tid; f < 400; f += 256) {
    int o = f / 10, rb = (f - o*10)*4;           // 4 consecutive r, fixed o
    float4 c0 = A0[f], c1 = A1[f], c2 = A2[f], c3 = A3[f];
    const float* p0 = (const float*)&c0; const float* p1 = (const float*)&c1;
    const float* p2 = (const float*)&c2; const float* p3 = (const float*)&c3;
    float res[4];
    float eo = el[o];
    #pragma unroll
    for (int j = 0; j < 4; ++j) {
      int r = rb + j;
      float d = prA[r] - X0C;
      float lp = ((p3[j]*d + p2[j])*d + p1[j])*d + p0[j];
      if (i == 0) {
        if (r == 0) ws[OFF_LA0 + o] = lp + eo;
        res[j] = 0.f;
      } else if (i == NN) {
        if (o == 1) ws[OFF_FIN + r] = lp;
        res[j] = 0.f;
      } else {
        res[j] = exp2f((lp + eo)*LOG2E - SCB);
      }
    }
    if (i > 0 && i < NN) pt4[f] = make_float4(res[0], res[1], res[2], res[3]);
  }
}

// KE: chunk-parallel vector scan (all-register, transposed loads) + finisher.
// 128 chunks x (<=2 warm + 4 real). Lane o loads its column as 10 float4s
// (contiguous 160B -> fully coalesced), ping-pong prefetch; matvec = 40 shfl+FMA.
// Renorm at warm/real boundary and every 4 real steps (no mixed groups).
// Birkhoff contraction ~5e-3/step => 2 warm-up steps: dir err ~2.5e-5.
// Chunk 0 starts exactly from la0. Last block reduces LACC and writes logZ.
__global__ __launch_bounds__(64) void ke_scan_fin(float* __restrict__ ws,
                                                  float* __restrict__ out)
{
  int c = blockIdx.x;           // 0..127
  int lane = threadIdx.x;
  int o = min(lane, KK - 1);    // lanes >=40 mirror column 39 (harmless dup)
  int s0 = 4*c;
  int len = min(4, 511 - s0);
  int w0 = (s0 >= 2) ? (s0 - 2) : 0;
  int warmN = s0 - w0;          // 0 (c==0) or 2
  int nst = warmN + len;        // 4, 5 or 6
  const float* P = ws + OFF_PT;
  float lacc = 0.f;
  float v;
  if (c == 0) {                 // exact start from la0
    float la = ws[OFF_LA0 + o];
    float m0 = la;
    #pragma unroll
    for (int m = 1; m <= 32; m <<= 1) m0 = fmaxf(m0, __shfl_xor(m0, m));
    v = __expf(la - m0);
    lacc = m0;
  } else {
    v = 1.f;
  }
  float pcA[KK], pcB[KK];
  int cnt = 0;

#define LOADCOL(buf, pi) do {                                       \
    const float4* g_ = (const float4*)(P + (size_t)(pi)*1600 + o*KK); \
    _Pragma("unroll")                                               \
    for (int q_ = 0; q_ < 10; ++q_) *(float4*)&buf[4*q_] = g_[q_];  \
  } while (0)

#define MSTEP(cur, nxt, k) do {                                 \
    if ((k) + 1 < nst) LOADCOL(nxt, w0 + (k) + 1);              \
    float a0_ = 0, a1_ = 0, a2_ = 0, a3_ = 0;                   \
    _Pragma("unroll")                                           \
    for (int r_ = 0; r_ < KK; r_ += 4) {                        \
      a0_ += __shfl(v, r_ + 0, 64)*cur[r_ + 0];                 \
      a1_ += __shfl(v, r_ + 1, 64)*cur[r_ + 1];                 \
      a2_ += __shfl(v, r_ + 2, 64)*cur[r_ + 2];                 \
      a3_ += __shfl(v, r_ + 3, 64)*cur[r_ + 3];                 \
    }                                                           \
    float s_ = (a0_ + a1_) + (a2_ + a3_);                       \
    bool isReal_ = (k) >= warmN;                                \
    if (isReal_) ++cnt;                                         \
    bool bound_ = ((k) == warmN - 1) || ((k) == nst - 1) ||     \
                  (isReal_ && (((k) - warmN + 1) & 3) == 0);    \
    if (bound_) {                                               \
      float mx_ = s_;                                           \
      _Pragma("unroll")                                         \
      for (int m_ = 1; m_ <= 32; m_ <<= 1)                      \
        mx_ = fmaxf(mx_, __shfl_xor(mx_, m_));                  \
      v = s_ / mx_;                                             \
      if (isReal_) {                                            \
        lacc += __logf(mx_) + (float)cnt*(SCB*LN2f);            \
        cnt = 0;                                                \
      }                                                         \
    } else {                                                    \
      v = s_;                                                   \
    }                                                           \
  } while (0)

  LOADCOL(pcA, w0);
  int k = 0;
  while (k + 2 <= nst) {
    MSTEP(pcA, pcB, k);
    MSTEP(pcB, pcA, k + 1);
    k += 2;
  }
  if (k < nst) MSTEP(pcA, pcB, k);
#undef MSTEP
#undef LOADCOL

  if (lane == 0) ws[OFF_LACC + c] = lacc;
  if (c == 127 && lane < KK) ws[OFF_VL + lane] = v;
  __threadfence();
  int last = 0;
  if (lane == 0) {
    int old = atomicAdd((int*)(ws + OFF_CTR), 1);
    last = (old == 127);
  }
  last = __shfl(last, 0, 64);
  if (last) {
    __threadfence();
    float l = ws[OFF_LACC + lane] + ws[OFF_LACC + 64 + lane];
    #pragma unroll
    for (int m = 1; m <= 32; m <<= 1) l += __shfl_xor(l, m);
    float tv = (lane < KK) ? ws[OFF_VL + lane]*__expf(ws[OFF_FIN + lane]) : 0.f;
    #pragma unroll
    for (int m = 1; m <= 32; m <<= 1) tv += __shfl_xor(tv, m);
    if (lane == 0) out[0] = l + __logf(tv);
  }
}

extern "C" void kernel_launch(void* const* d_in, const int* in_sizes, int n_in,
                              void* d_out, int out_size, void* d_ws, size_t ws_size,
                              hipStream_t stream) {
  const float* E     = (const float*)d_in[0];
  const float* M     = (const float*)d_in[1];
  const float* MP    = (const float*)d_in[2];
  const float* T     = (const float*)d_in[3];
  const float* UA    = (const float*)d_in[4];
  const float* UB    = (const float*)d_in[5];
  const float* WlinA = (const float*)d_in[6];
  const float* WlinB = (const float*)d_in[7];
  const int*   words = (const int*)d_in[8];
  float* ws  = (float*)d_ws;
  float* out = (float*)d_out;

  ka_prep<<<dim3(NN + 1 + KK), dim3(256), 0, stream>>>(E, M, MP, T, UA, UB, WlinB, words, ws);
  kb_rnn_mac<<<dim3(192), dim3(64), 0, stream>>>(M, MP, WlinA, ws);
  kd_expand<<<dim3(NN + 1), dim3(256), 0, stream>>>(UA, UB, ws);
  ke_scan_fin<<<dim3(128), dim3(64), 0, stream>>>(ws, out);
}